// Round 1
// baseline (254.516 us; speedup 1.0000x reference)
//
#include <hip/hip_runtime.h>
#include <hip/hip_bf16.h>

using bf16 = __hip_bfloat16;
using bf16x8 = __attribute__((ext_vector_type(8))) short;   // 8 bf16 = 4 VGPRs (MFMA A/B frag)
using f32x4  = __attribute__((ext_vector_type(4))) float;   // MFMA C/D frag

#define B_    16
#define HIM   56
#define WIM   56
#define HD    512
#define NHEAD 8
#define DH    64
#define NTOK  (HIM*WIM)      // 3136
#define M_    (B_*NTOK)      // 50176
#define K49   49

// ---- async global->LDS, 16B per lane, LDS dest must be wave-uniform base ----
__device__ __forceinline__ void gload_lds16(const void* g, void* l) {
  __builtin_amdgcn_global_load_lds(
      (__attribute__((address_space(1))) const void*)g,
      (__attribute__((address_space(3))) void*)l, 16, 0, 0);
}

// ---------------- kernel: fp32 -> bf16 convert (vectorized, 8 elems/thread) ----------------
__global__ __launch_bounds__(256) void cvt_x_kernel(const float* __restrict__ in,
                                                    bf16* __restrict__ out) {
  size_t i = ((size_t)blockIdx.x * 256 + threadIdx.x) * 8;
  float4 a = *(const float4*)(in + i);
  float4 b = *(const float4*)(in + i + 4);
  union { uint4 v; bf16 h[8]; } o;
  o.h[0] = __float2bfloat16(a.x); o.h[1] = __float2bfloat16(a.y);
  o.h[2] = __float2bfloat16(a.z); o.h[3] = __float2bfloat16(a.w);
  o.h[4] = __float2bfloat16(b.x); o.h[5] = __float2bfloat16(b.y);
  o.h[6] = __float2bfloat16(b.z); o.h[7] = __float2bfloat16(b.w);
  *(uint4*)(out + i) = o.v;
}

// ---------------- kernel: W (K x N) -> Wt (N x K) bf16 ----------------
__global__ __launch_bounds__(256) void cvt_transpose_kernel(const float* __restrict__ in,
                                                            bf16* __restrict__ out,
                                                            int K, int N) {
  int idx = blockIdx.x * 256 + threadIdx.x;   // grid covers K*N exactly
  int k = idx / N, n = idx - k * N;
  out[(size_t)n * K + k] = __float2bfloat16(in[idx]);
}

// ---------------- kernel: C(MxN) = A(MxK) * Bt(NxK)^T, bf16 MFMA, 128x128 tile, BK=32 ----
// LDS XOR swizzle: 16B slot' = slot ^ ((row>>1)&3); applied to global SOURCE (linear LDS
// dest for global_load_lds) and to ds_read address — same involution (rule #21).
template<bool OUT_BF16, bool BIAS>
__global__ __launch_bounds__(256) void gemm128_kernel(
    const bf16* __restrict__ A,    // M x K row-major (K=512)
    const bf16* __restrict__ Bt,   // N x K row-major
    void* __restrict__ Cp,
    const float* __restrict__ bias,
    int M, int N, int K)
{
  __shared__ alignas(16) bf16 lds[2][2][128 * 32];   // [buf][A/B][row*32 + slot*8]
  const int tid  = threadIdx.x;
  const int lane = tid & 63, wid = tid >> 6;
  const int l15  = lane & 15, kq = lane >> 4;
  const int wm   = wid >> 1,  wn = wid & 1;
  const long arow0 = (long)blockIdx.y * 128;
  const long bcol0 = (long)blockIdx.x * 128;

  auto stage = [&](int buf, int kt) {
    const bf16* gA = A  + arow0 * K + kt * 32;
    const bf16* gB = Bt + bcol0 * K + kt * 32;
#pragma unroll
    for (int c = 0; c < 2; ++c) {
      int s   = c * 256 + tid;         // 16B-slot id within 8KB tile (512 slots)
      int row = s >> 2, sl = s & 3;
      int gs  = sl ^ ((row >> 1) & 3); // pre-swizzled global source slot
      const char* pa = (const char*)(gA + (long)row * K) + gs * 16;
      const char* pb = (const char*)(gB + (long)row * K) + gs * 16;
      bf16* la = (bf16*)&lds[buf][0][(c * 256 + wid * 64) * 8];  // wave-uniform
      bf16* lb = (bf16*)&lds[buf][1][(c * 256 + wid * 64) * 8];
      gload_lds16(pa, la);
      gload_lds16(pb, lb);
    }
  };

  f32x4 acc[4][4] = {};
  stage(0, 0);
  __syncthreads();
  const int nk = K >> 5;
  int buf = 0;
#pragma unroll 1
  for (int kt = 0; kt < nk; ++kt) {
    if (kt + 1 < nk) stage(buf ^ 1, kt + 1);
    bf16x8 af[4], br[4];
#pragma unroll
    for (int mt = 0; mt < 4; ++mt) {
      int row  = wm * 64 + mt * 16 + l15;
      int slot = kq ^ ((row >> 1) & 3);
      af[mt] = *(const bf16x8*)&lds[buf][0][row * 32 + slot * 8];
    }
#pragma unroll
    for (int nt = 0; nt < 4; ++nt) {
      int row  = wn * 64 + nt * 16 + l15;
      int slot = kq ^ ((row >> 1) & 3);
      br[nt] = *(const bf16x8*)&lds[buf][1][row * 32 + slot * 8];
    }
#pragma unroll
    for (int mt = 0; mt < 4; ++mt)
#pragma unroll
      for (int nt = 0; nt < 4; ++nt)
        acc[mt][nt] = __builtin_amdgcn_mfma_f32_16x16x32_bf16(af[mt], br[nt], acc[mt][nt], 0, 0, 0);
    __syncthreads();
    buf ^= 1;
  }

  const long crow0 = arow0 + wm * 64;
  const long ccol0 = bcol0 + wn * 64;
#pragma unroll
  for (int mt = 0; mt < 4; ++mt) {
#pragma unroll
    for (int nt = 0; nt < 4; ++nt) {
      long col = ccol0 + nt * 16 + l15;
      float bv = BIAS ? bias[col] : 0.f;
#pragma unroll
      for (int r = 0; r < 4; ++r) {
        long row = crow0 + mt * 16 + kq * 4 + r;  // C/D: col=lane&15, row=(lane>>4)*4+reg
        if (OUT_BF16)
          ((bf16*)Cp)[row * N + col] = __float2bfloat16(acc[mt][nt][r]);
        else
          ((float*)Cp)[row * N + col] = acc[mt][nt][r] + bv;
      }
    }
  }
}

// ---------------- kernel: windowed attention, one WG per (b, window p, head g) ------------
// qkv: [B][3136][1536] bf16 (cols: q 0-511 | k 512-1023 | v 1024-1535), head g slice = g*64
// rb : [8][49][49] fp32 ; outa: [B][3136][512] bf16
__global__ __launch_bounds__(256) void attn_win_kernel(
    const bf16* __restrict__ qkv, const float* __restrict__ rb, bf16* __restrict__ outa)
{
  __shared__ alignas(16) bf16 Qs[64 * 72];  // [token][chan], stride 72 (144B -> 2-way free)
  __shared__ alignas(16) bf16 Ks[64 * 72];
  __shared__ alignas(16) bf16 Vt[64 * 72];  // transposed: [chan][token]
  __shared__ alignas(16) bf16 Ps[64 * 72];  // probabilities [q][k]
  const int tid = threadIdx.x, lane = tid & 63, wid = tid >> 6;
  const int p = blockIdx.x, g = blockIdx.y, b = blockIdx.z;
  const int sh = p >> 3, sw = p & 7;
  const size_t nb = (size_t)b * NTOK;
  const int c8 = (tid & 7) * 8;

  // stage Q,K row-major + V transposed; zero-fill pad tokens 49..63
#pragma unroll
  for (int it = 0; it < 2; ++it) {
    int t = (tid >> 3) + it * 32;
    uint4 vq = {0, 0, 0, 0}, vk = vq, vv = vq;
    if (t < K49) {
      int ph = t / 7, pw = t - ph * 7;
      int n = (sh * 7 + ph) * WIM + sw * 7 + pw;
      const bf16* src = qkv + (nb + n) * 1536 + g * 64 + c8;
      vq = *(const uint4*)(src);
      vk = *(const uint4*)(src + 512);
      vv = *(const uint4*)(src + 1024);
    }
    *(uint4*)&Qs[t * 72 + c8] = vq;
    *(uint4*)&Ks[t * 72 + c8] = vk;
    union { uint4 u; unsigned short s[8]; } uv; uv.u = vv;
    unsigned short* vt16 = (unsigned short*)Vt;
#pragma unroll
    for (int e = 0; e < 8; ++e) vt16[(c8 + e) * 72 + t] = uv.s[e];
  }
  __syncthreads();

  const int l15 = lane & 15, kq = lane >> 4;
  // ---- S = Q K^T (wave w owns q rows 16w..16w+15; 4 col tiles) ----
  bf16x8 aq[2];
#pragma unroll
  for (int kk = 0; kk < 2; ++kk)
    aq[kk] = *(const bf16x8*)&Qs[(wid * 16 + l15) * 72 + kk * 32 + kq * 8];
  float sv[4][4];   // [ct][r]
#pragma unroll
  for (int ct = 0; ct < 4; ++ct) {
    f32x4 acc = {0.f, 0.f, 0.f, 0.f};
#pragma unroll
    for (int kk = 0; kk < 2; ++kk) {
      bf16x8 bk = *(const bf16x8*)&Ks[(ct * 16 + l15) * 72 + kk * 32 + kq * 8];
      acc = __builtin_amdgcn_mfma_f32_16x16x32_bf16(aq[kk], bk, acc, 0, 0, 0);
    }
    int kcol = ct * 16 + l15;
#pragma unroll
    for (int r = 0; r < 4; ++r) {
      int q = wid * 16 + kq * 4 + r;
      float bias = (q < K49 && kcol < K49) ? rb[((size_t)g * K49 + q) * K49 + kcol] : 0.f;
      float v = (acc[r] + bias) * 0.125f;          // (S + rel_bias) * dh^-0.5
      sv[ct][r] = (kcol < K49) ? v : -1e30f;       // mask pad keys
    }
  }
  // ---- softmax over keys (row q lives in the 16 lanes sharing kq) ----
#pragma unroll
  for (int r = 0; r < 4; ++r) {
    float m = fmaxf(fmaxf(sv[0][r], sv[1][r]), fmaxf(sv[2][r], sv[3][r]));
#pragma unroll
    for (int d = 1; d < 16; d <<= 1) m = fmaxf(m, __shfl_xor(m, d));
    float e0 = __expf(sv[0][r] - m), e1 = __expf(sv[1][r] - m);
    float e2 = __expf(sv[2][r] - m), e3 = __expf(sv[3][r] - m);
    float s = e0 + e1 + e2 + e3;
#pragma unroll
    for (int d = 1; d < 16; d <<= 1) s += __shfl_xor(s, d);
    float inv = 1.0f / s;
    int q = wid * 16 + kq * 4 + r;
    Ps[q * 72 +  0 + l15] = __float2bfloat16(e0 * inv);
    Ps[q * 72 + 16 + l15] = __float2bfloat16(e1 * inv);
    Ps[q * 72 + 32 + l15] = __float2bfloat16(e2 * inv);
    Ps[q * 72 + 48 + l15] = __float2bfloat16(e3 * inv);
  }
  __syncthreads();
  // ---- O = P V ----
  bf16x8 ap[2];
#pragma unroll
  for (int kk = 0; kk < 2; ++kk)
    ap[kk] = *(const bf16x8*)&Ps[(wid * 16 + l15) * 72 + kk * 32 + kq * 8];
#pragma unroll
  for (int ct = 0; ct < 4; ++ct) {
    f32x4 acc = {0.f, 0.f, 0.f, 0.f};
#pragma unroll
    for (int kk = 0; kk < 2; ++kk) {
      bf16x8 bv = *(const bf16x8*)&Vt[(ct * 16 + l15) * 72 + kk * 32 + kq * 8];
      acc = __builtin_amdgcn_mfma_f32_16x16x32_bf16(ap[kk], bv, acc, 0, 0, 0);
    }
#pragma unroll
    for (int r = 0; r < 4; ++r) {
      int q = wid * 16 + kq * 4 + r;
      if (q < K49) {
        int ph = q / 7, pw = q - ph * 7;
        int n = (sh * 7 + ph) * WIM + sw * 7 + pw;
        outa[(nb + n) * HD + g * 64 + ct * 16 + l15] = __float2bfloat16(acc[r]);
      }
    }
  }
}

// ---------------- launch ----------------
extern "C" void kernel_launch(void* const* d_in, const int* in_sizes, int n_in,
                              void* d_out, int out_size, void* d_ws, size_t ws_size,
                              hipStream_t stream) {
  (void)in_sizes; (void)n_in; (void)out_size;
  const float* x     = (const float*)d_in[0];
  // d_in[1] = mask: all-False with zero padding (56 % 7 == 0) -> no-op, skipped
  const float* wqkv  = (const float*)d_in[2];
  const float* wproj = (const float*)d_in[3];
  const float* bproj = (const float*)d_in[4];
  const float* rb    = (const float*)d_in[5];
  // d_in[6], d_in[7] = H, W (56, 56) constants

  // workspace layout (207,618,048 bytes total)
  char* ws = (char*)d_ws;
  bf16* x_bf    = (bf16*)(ws);              // 51,380,224 B ; reused as attnout after GEMM1
  bf16* wqkv_t  = (bf16*)(ws + 51380224);   //  1,572,864 B
  bf16* wproj_t = (bf16*)(ws + 52953088);   //    524,288 B
  bf16* qkv     = (bf16*)(ws + 53477376);   // 154,140,672 B
  bf16* attno   = x_bf;
  float* out    = (float*)d_out;
  if (ws_size < 207618048) return;  // fail visibly rather than corrupt

  cvt_x_kernel<<<dim3(12544), 256, 0, stream>>>(x, x_bf);                       // 50176*512/8/256
  cvt_transpose_kernel<<<dim3(3072), 256, 0, stream>>>(wqkv, wqkv_t, 512, 1536);
  cvt_transpose_kernel<<<dim3(1024), 256, 0, stream>>>(wproj, wproj_t, 512, 512);
  gemm128_kernel<true, false><<<dim3(12, 392), 256, 0, stream>>>(
      x_bf, wqkv_t, (void*)qkv, nullptr, M_, 1536, 512);
  attn_win_kernel<<<dim3(64, NHEAD, B_), 256, 0, stream>>>(qkv, rb, attno);
  gemm128_kernel<false, true><<<dim3(4, 392), 256, 0, stream>>>(
      attno, wproj_t, (void*)out, bproj, M_, 512, 512);
}

// Round 2
// 250.934 us; speedup vs baseline: 1.0143x; 1.0143x over previous
//
#include <hip/hip_runtime.h>
#include <hip/hip_bf16.h>

using bf16 = __hip_bfloat16;
using bf16x8 = __attribute__((ext_vector_type(8))) short;   // 8 bf16 = 4 VGPRs (MFMA A/B frag)
using f32x4  = __attribute__((ext_vector_type(4))) float;   // MFMA C/D frag

#define B_    16
#define HIM   56
#define WIM   56
#define HD    512
#define NHEAD 8
#define DH    64
#define NTOK  (HIM*WIM)      // 3136
#define M_    (B_*NTOK)      // 50176
#define K49   49

// ---- async global->LDS, 16B per lane, LDS dest must be wave-uniform base ----
__device__ __forceinline__ void gload_lds16(const void* g, void* l) {
  __builtin_amdgcn_global_load_lds(
      (__attribute__((address_space(1))) const void*)g,
      (__attribute__((address_space(3))) void*)l, 16, 0, 0);
}

// ---------------- kernel: fp32 -> bf16 convert (vectorized, 8 elems/thread) ----------------
__global__ __launch_bounds__(256) void cvt_x_kernel(const float* __restrict__ in,
                                                    bf16* __restrict__ out) {
  size_t i = ((size_t)blockIdx.x * 256 + threadIdx.x) * 8;
  float4 a = *(const float4*)(in + i);
  float4 b = *(const float4*)(in + i + 4);
  union { uint4 v; bf16 h[8]; } o;
  o.h[0] = __float2bfloat16(a.x); o.h[1] = __float2bfloat16(a.y);
  o.h[2] = __float2bfloat16(a.z); o.h[3] = __float2bfloat16(a.w);
  o.h[4] = __float2bfloat16(b.x); o.h[5] = __float2bfloat16(b.y);
  o.h[6] = __float2bfloat16(b.z); o.h[7] = __float2bfloat16(b.w);
  *(uint4*)(out + i) = o.v;
}

// ---------------- kernel: W (K x N) -> Wt (N x K) bf16 ----------------
__global__ __launch_bounds__(256) void cvt_transpose_kernel(const float* __restrict__ in,
                                                            bf16* __restrict__ out,
                                                            int K, int N) {
  int idx = blockIdx.x * 256 + threadIdx.x;   // grid covers K*N exactly
  int k = idx / N, n = idx - k * N;
  out[(size_t)n * K + k] = __float2bfloat16(in[idx]);
}

// ---------------- kernel: C(MxN) = A(MxK) * Bt(NxK)^T, bf16 MFMA, 128x128 tile, BK=32 ----
// Depth-2 prefetch pipeline: 3 LDS buffers, stage tile t+2 while computing tile t.
// Counted vmcnt(4) at iteration top (tile t landed, tile t+1 in flight) — never drain
// to 0 in the main loop (T4). Raw s_barrier + memory-clobber asm (not __syncthreads).
// LDS XOR swizzle: 16B slot' = slot ^ ((row>>1)&3) — linear LDS dest (global_load_lds),
// pre-swizzled global SOURCE, same involution on ds_read (rule #21). Verified round 1:
// SQ_LDS_BANK_CONFLICT == 0.
template<bool OUT_BF16, bool BIAS>
__global__ __launch_bounds__(256, 3) void gemm128_kernel(
    const bf16* __restrict__ A,    // M x K row-major (K=512)
    const bf16* __restrict__ Bt,   // N x K row-major
    void* __restrict__ Cp,
    const float* __restrict__ bias,
    int M, int N, int K, int NBX)
{
  __shared__ alignas(16) bf16 lds[3][2][128 * 32];   // 3 bufs x (A,B) x 8KB = 48 KB
  const int tid  = threadIdx.x;
  const int lane = tid & 63, wid = tid >> 6;
  const int l15  = lane & 15, kq = lane >> 4;
  const int wm   = wid >> 1,  wn = wid & 1;
  // XCD-aware swizzle (launches guarantee gridDim.x % 8 == 0)
  const int cpx = gridDim.x >> 3;
  const int wg  = (blockIdx.x & 7) * cpx + (blockIdx.x >> 3);
  const int by  = wg / NBX, bx = wg - by * NBX;
  const long arow0 = (long)by * 128;
  const long bcol0 = (long)bx * 128;

  auto stage = [&](int buf, int kt) {
    const bf16* gA = A  + arow0 * K + kt * 32;
    const bf16* gB = Bt + bcol0 * K + kt * 32;
#pragma unroll
    for (int c = 0; c < 2; ++c) {
      int s   = c * 256 + tid;         // 16B-slot id within 8KB tile (512 slots)
      int row = s >> 2, sl = s & 3;
      int gs  = sl ^ ((row >> 1) & 3); // pre-swizzled global source slot
      gload_lds16((const char*)(gA + (long)row * K) + gs * 16,
                  (bf16*)&lds[buf][0][(c * 256 + wid * 64) * 8]);   // wave-uniform dest
      gload_lds16((const char*)(gB + (long)row * K) + gs * 16,
                  (bf16*)&lds[buf][1][(c * 256 + wid * 64) * 8]);
    }
  };

  f32x4 acc[4][4] = {};
  const int NT = K >> 5;     // 16 K-tiles
  stage(0, 0);               // prologue: 2 tiles in flight (8 vmcnt events)
  stage(1, 1);
  int cur = 0;
#pragma unroll 1
  for (int t = 0; t < NT; ++t) {
    // wait: tile t landed (oldest 4 loads), tile t+1 stays in flight
    if (t + 1 < NT) asm volatile("s_waitcnt vmcnt(4)" ::: "memory");
    else            asm volatile("s_waitcnt vmcnt(0)" ::: "memory");
    __builtin_amdgcn_s_barrier();
    asm volatile("" ::: "memory");     // fence: no LDS reads hoist above barrier
    if (t + 2 < NT) { int nb = cur + 2; if (nb >= 3) nb -= 3; stage(nb, t + 2); }

    bf16x8 af[4], br[4];
#pragma unroll
    for (int mt = 0; mt < 4; ++mt) {
      int row  = wm * 64 + mt * 16 + l15;
      int slot = kq ^ ((row >> 1) & 3);
      af[mt] = *(const bf16x8*)&lds[cur][0][row * 32 + slot * 8];
    }
#pragma unroll
    for (int nt2 = 0; nt2 < 4; ++nt2) {
      int row  = wn * 64 + nt2 * 16 + l15;
      int slot = kq ^ ((row >> 1) & 3);
      br[nt2] = *(const bf16x8*)&lds[cur][1][row * 32 + slot * 8];
    }
    __builtin_amdgcn_s_setprio(1);
#pragma unroll
    for (int mt = 0; mt < 4; ++mt)
#pragma unroll
      for (int nt2 = 0; nt2 < 4; ++nt2)
        acc[mt][nt2] = __builtin_amdgcn_mfma_f32_16x16x32_bf16(af[mt], br[nt2], acc[mt][nt2], 0, 0, 0);
    __builtin_amdgcn_s_setprio(0);
    ++cur; if (cur >= 3) cur = 0;
  }

  // epilogue: nontemporal stores (avoid C write-allocate fetch through L2)
  const long crow0 = arow0 + wm * 64;
  const long ccol0 = bcol0 + wn * 64;
#pragma unroll
  for (int mt = 0; mt < 4; ++mt) {
#pragma unroll
    for (int nt2 = 0; nt2 < 4; ++nt2) {
      long col = ccol0 + nt2 * 16 + l15;
      float bv = BIAS ? bias[col] : 0.f;
#pragma unroll
      for (int r = 0; r < 4; ++r) {
        long row = crow0 + mt * 16 + kq * 4 + r;  // C/D: col=lane&15, row=(lane>>4)*4+reg
        if (OUT_BF16) {
          bf16 h = __float2bfloat16(acc[mt][nt2][r]);
          __builtin_nontemporal_store(*(const unsigned short*)&h,
                                      (unsigned short*)Cp + row * N + col);
        } else {
          __builtin_nontemporal_store(acc[mt][nt2][r] + bv, (float*)Cp + row * N + col);
        }
      }
    }
  }
}

// ---------------- kernel: windowed attention, one WG per (b, window p, head g) ------------
// qkv: [B][3136][1536] bf16 (cols: q 0-511 | k 512-1023 | v 1024-1535), head g slice = g*64
// rb : [8][49][49] fp32 ; outa: [B][3136][512] bf16
__global__ __launch_bounds__(256) void attn_win_kernel(
    const bf16* __restrict__ qkv, const float* __restrict__ rb, bf16* __restrict__ outa)
{
  __shared__ alignas(16) bf16 Qs[64 * 72];  // [token][chan], stride 72 (144B -> 2-way free)
  __shared__ alignas(16) bf16 Ks[64 * 72];
  __shared__ alignas(16) bf16 Vt[64 * 72];  // transposed: [chan][token]
  __shared__ alignas(16) bf16 Ps[64 * 72];  // probabilities [q][k]
  const int tid = threadIdx.x, lane = tid & 63, wid = tid >> 6;
  const int p = blockIdx.x, g = blockIdx.y, b = blockIdx.z;
  const int sh = p >> 3, sw = p & 7;
  const size_t nb = (size_t)b * NTOK;
  const int c8 = (tid & 7) * 8;

  // stage Q,K row-major + V transposed; zero-fill pad tokens 49..63
#pragma unroll
  for (int it = 0; it < 2; ++it) {
    int t = (tid >> 3) + it * 32;
    uint4 vq = {0, 0, 0, 0}, vk = vq, vv = vq;
    if (t < K49) {
      int ph = t / 7, pw = t - ph * 7;
      int n = (sh * 7 + ph) * WIM + sw * 7 + pw;
      const bf16* src = qkv + (nb + n) * 1536 + g * 64 + c8;
      vq = *(const uint4*)(src);
      vk = *(const uint4*)(src + 512);
      vv = *(const uint4*)(src + 1024);
    }
    *(uint4*)&Qs[t * 72 + c8] = vq;
    *(uint4*)&Ks[t * 72 + c8] = vk;
    union { uint4 u; unsigned short s[8]; } uv; uv.u = vv;
    unsigned short* vt16 = (unsigned short*)Vt;
#pragma unroll
    for (int e = 0; e < 8; ++e) vt16[(c8 + e) * 72 + t] = uv.s[e];
  }
  __syncthreads();

  const int l15 = lane & 15, kq = lane >> 4;
  // ---- S = Q K^T (wave w owns q rows 16w..16w+15; 4 col tiles) ----
  bf16x8 aq[2];
#pragma unroll
  for (int kk = 0; kk < 2; ++kk)
    aq[kk] = *(const bf16x8*)&Qs[(wid * 16 + l15) * 72 + kk * 32 + kq * 8];
  float sv[4][4];   // [ct][r]
#pragma unroll
  for (int ct = 0; ct < 4; ++ct) {
    f32x4 acc = {0.f, 0.f, 0.f, 0.f};
#pragma unroll
    for (int kk = 0; kk < 2; ++kk) {
      bf16x8 bk = *(const bf16x8*)&Ks[(ct * 16 + l15) * 72 + kk * 32 + kq * 8];
      acc = __builtin_amdgcn_mfma_f32_16x16x32_bf16(aq[kk], bk, acc, 0, 0, 0);
    }
    int kcol = ct * 16 + l15;
#pragma unroll
    for (int r = 0; r < 4; ++r) {
      int q = wid * 16 + kq * 4 + r;
      float bias = (q < K49 && kcol < K49) ? rb[((size_t)g * K49 + q) * K49 + kcol] : 0.f;
      float v = (acc[r] + bias) * 0.125f;          // (S + rel_bias) * dh^-0.5
      sv[ct][r] = (kcol < K49) ? v : -1e30f;       // mask pad keys
    }
  }
  // ---- softmax over keys (row q lives in the 16 lanes sharing kq) ----
#pragma unroll
  for (int r = 0; r < 4; ++r) {
    float m = fmaxf(fmaxf(sv[0][r], sv[1][r]), fmaxf(sv[2][r], sv[3][r]));
#pragma unroll
    for (int d = 1; d < 16; d <<= 1) m = fmaxf(m, __shfl_xor(m, d));
    float e0 = __expf(sv[0][r] - m), e1 = __expf(sv[1][r] - m);
    float e2 = __expf(sv[2][r] - m), e3 = __expf(sv[3][r] - m);
    float s = e0 + e1 + e2 + e3;
#pragma unroll
    for (int d = 1; d < 16; d <<= 1) s += __shfl_xor(s, d);
    float inv = 1.0f / s;
    int q = wid * 16 + kq * 4 + r;
    Ps[q * 72 +  0 + l15] = __float2bfloat16(e0 * inv);
    Ps[q * 72 + 16 + l15] = __float2bfloat16(e1 * inv);
    Ps[q * 72 + 32 + l15] = __float2bfloat16(e2 * inv);
    Ps[q * 72 + 48 + l15] = __float2bfloat16(e3 * inv);
  }
  __syncthreads();
  // ---- O = P V ----
  bf16x8 ap[2];
#pragma unroll
  for (int kk = 0; kk < 2; ++kk)
    ap[kk] = *(const bf16x8*)&Ps[(wid * 16 + l15) * 72 + kk * 32 + kq * 8];
#pragma unroll
  for (int ct = 0; ct < 4; ++ct) {
    f32x4 acc = {0.f, 0.f, 0.f, 0.f};
#pragma unroll
    for (int kk = 0; kk < 2; ++kk) {
      bf16x8 bv = *(const bf16x8*)&Vt[(ct * 16 + l15) * 72 + kk * 32 + kq * 8];
      acc = __builtin_amdgcn_mfma_f32_16x16x32_bf16(ap[kk], bv, acc, 0, 0, 0);
    }
#pragma unroll
    for (int r = 0; r < 4; ++r) {
      int q = wid * 16 + kq * 4 + r;
      if (q < K49) {
        int ph = q / 7, pw = q - ph * 7;
        int n = (sh * 7 + ph) * WIM + sw * 7 + pw;
        outa[(nb + n) * HD + g * 64 + ct * 16 + l15] = __float2bfloat16(acc[r]);
      }
    }
  }
}

// ---------------- launch ----------------
extern "C" void kernel_launch(void* const* d_in, const int* in_sizes, int n_in,
                              void* d_out, int out_size, void* d_ws, size_t ws_size,
                              hipStream_t stream) {
  (void)in_sizes; (void)n_in; (void)out_size;
  const float* x     = (const float*)d_in[0];
  // d_in[1] = mask: all-False with zero padding (56 % 7 == 0) -> no-op, skipped
  const float* wqkv  = (const float*)d_in[2];
  const float* wproj = (const float*)d_in[3];
  const float* bproj = (const float*)d_in[4];
  const float* rb    = (const float*)d_in[5];
  // d_in[6], d_in[7] = H, W (56, 56) constants

  // workspace layout (207,618,048 bytes total)
  char* ws = (char*)d_ws;
  bf16* x_bf    = (bf16*)(ws);              // 51,380,224 B ; reused as attnout after GEMM1
  bf16* wqkv_t  = (bf16*)(ws + 51380224);   //  1,572,864 B
  bf16* wproj_t = (bf16*)(ws + 52953088);   //    524,288 B
  bf16* qkv     = (bf16*)(ws + 53477376);   // 154,140,672 B
  bf16* attno   = x_bf;
  float* out    = (float*)d_out;
  if (ws_size < 207618048) return;  // fail visibly rather than corrupt

  cvt_x_kernel<<<dim3(12544), 256, 0, stream>>>(x, x_bf);                       // 50176*512/8/256
  cvt_transpose_kernel<<<dim3(3072), 256, 0, stream>>>(wqkv, wqkv_t, 512, 1536);
  cvt_transpose_kernel<<<dim3(1024), 256, 0, stream>>>(wproj, wproj_t, 512, 512);
  // GEMM1: M=50176, N=1536 -> 392 x 12 = 4704 blocks (4704 % 8 == 0)
  gemm128_kernel<true, false><<<dim3(4704), 256, 0, stream>>>(
      x_bf, wqkv_t, (void*)qkv, nullptr, M_, 1536, 512, 12);
  attn_win_kernel<<<dim3(64, NHEAD, B_), 256, 0, stream>>>(qkv, rb, attno);
  // GEMM2: M=50176, N=512 -> 392 x 4 = 1568 blocks (1568 % 8 == 0)
  gemm128_kernel<false, true><<<dim3(1568), 256, 0, stream>>>(
      attno, wproj_t, (void*)out, bproj, M_, 512, 512, 4);
}